// Round 11
// baseline (628.664 us; speedup 1.0000x reference)
//
#include <hip/hip_runtime.h>

typedef __attribute__((ext_vector_type(8))) short bf16x8;
typedef __attribute__((ext_vector_type(4))) float f32x4;
typedef __attribute__((ext_vector_type(4))) short short4v;
typedef __attribute__((ext_vector_type(2))) short short2v;

__device__ __forceinline__ unsigned short f2bf(float x){
  unsigned u = __float_as_uint(x);
  return (unsigned short)((u + 0x7FFFu + ((u>>16)&1u)) >> 16);
}
__device__ __forceinline__ float bf2f(unsigned short b){
  return __uint_as_float(((unsigned)b)<<16);
}

typedef const __attribute__((address_space(1))) void* gas_t;
typedef __attribute__((address_space(3))) void* las_t;
__device__ __forceinline__ void gl16(const void* g, void* l){
  __builtin_amdgcn_global_load_lds((gas_t)g, (las_t)l, 16, 0, 0);
}

// ---------------- workspace layout (bytes), ws_size ~784 MiB ----------------
static constexpr size_t O_FHI  = 0;              // fhi bf16 [25088][2048] (later xxt f32)
static constexpr size_t O_FLO  = 102760448;      // flo bf16 [25088][2048]
static constexpr size_t O_XHI  = 205520896;      // x_hi bf16 [128][512][256]
static constexpr size_t O_XLO  = 239075328;      // x_lo bf16 (later ypad [b][8][256][64])
static constexpr size_t O_XT   = 272629760;      // xT bf16 [128][224][512]
static constexpr size_t O_AMAT = 301989888;      // a bf16 [128][512][512]
static constexpr size_t O_WH   = 369098752;      // wh bf16 [512][2048]
static constexpr size_t O_WL   = 371195904;      // wl
static constexpr size_t O_W3B  = 373293056;      // w3c bf16 [8][9][512][64]
static constexpr size_t O_PAR  = 378011648;      // s1,t1,s2,t2
static constexpr size_t O_FC1T = 378019840;      // fc1T f32 [512][200]
static constexpr size_t O_FC2T = 378429440;      // fc2T f32 [200][200]
static constexpr size_t O_ZBAR = 378589440;      // zbar f32 [128][512] (sum)

// ---------------- fused prep kernel (ranges over blockIdx) ----------------
__global__ __launch_bounds__(256) void k_prep(
    const float* wr, unsigned short* wh, unsigned short* wl,
    const float* w3, unsigned short* w3c,
    const float* fc1w, float* fc1T, const float* fc2w, float* fc2T,
    const float* br, const float* g1, const float* be1, const float* m1, const float* v1,
    const float* b3, const float* g2, const float* be2, const float* m2, const float* v2,
    float* par, unsigned short* xhi, unsigned short* xlo){
  int blk = blockIdx.x, t = threadIdx.x;
  if (blk < 4096){                       // wh/wl split: 512x2048
    int idx = blk*256 + t;
    int c = idx >> 11, k = idx & 2047;
    float v = wr[(size_t)c*2048 + k];
    unsigned short h = f2bf(v);
    wh[(size_t)c*2048+k] = h; wl[(size_t)c*2048+k] = f2bf(v - bf2f(h));
  } else if (blk < 13312){               // w3c repack: 512x4608
    int i = (blk-4096)*256 + t;
    int co = i / 4608, k = i - co*4608;
    int ci0b = k / 576, r2 = k - ci0b*576;
    int tap = r2 >> 6, cio = r2 & 63;
    w3c[(((size_t)ci0b*9+tap)*512+co)*64+cio] =
        f2bf(w3[((size_t)co*512 + ci0b*64+cio)*9 + tap]);
  } else if (blk < 13712){               // fc1T
    int i = (blk-13312)*256 + t;
    int k = i/200, j = i - k*200;
    fc1T[i] = fc1w[j*512+k];
  } else if (blk < 13869){               // fc2T
    int i = (blk-13712)*256 + t;
    if (i < 40000){ int k = i/200, j = i - k*200; fc2T[i] = fc2w[j*200+k]; }
  } else if (blk < 13871){               // BN params
    int c = (blk-13869)*256 + t;
    if (c < 512){
      float s1 = g1[c]*rsqrtf(v1[c]+1e-5f);
      par[c] = s1; par[512+c] = (br[c]-m1[c])*s1 + be1[c];
      float s2 = g2[c]*rsqrtf(v2[c]+1e-5f);
      par[1024+c] = s2; par[1536+c] = (b3[c]-m2[c])*s2 + be2[c];
    }
  } else {                               // zero pad cols [192,256) of xhi/xlo
    int rr = (blk-13871)*256 + t;        // 65536 rows
    float4 z = {0.f,0.f,0.f,0.f};
    float4* a = (float4*)(xhi + (size_t)rr*256 + 192);
    float4* bq = (float4*)(xlo + (size_t)rr*256 + 192);
    #pragma unroll
    for (int q=0;q<8;++q){ a[q]=z; bq[q]=z; }
  }
}

// transpose+split feature -> dense fhi/flo bf16 [b*196+p][2048], ushort2 writes
__global__ __launch_bounds__(256) void k_featT(const float* __restrict__ feat,
        unsigned short* __restrict__ fhi, unsigned short* __restrict__ flo){
  __shared__ float tile[64][33];
  int b = blockIdx.z;
  int ci0 = blockIdx.y*64, p0 = blockIdx.x*32;
  int t = threadIdx.x;
  int j = t & 31, i0 = t >> 5;
  for (int rep=0; rep<8; ++rep){
    int i = rep*8 + i0;
    int p = p0 + j;
    tile[i][j] = (p<196) ? feat[((size_t)b*2048 + ci0 + i)*196 + p] : 0.f;
  }
  __syncthreads();
  int j2 = t & 31;
  int jj0 = t >> 5;
  for (int rep=0; rep<4; ++rep){
    int jj = rep*8 + jj0;
    int p = p0 + jj;
    if (p < 196){
      float v0 = tile[2*j2][jj], v1 = tile[2*j2+1][jj];
      unsigned short h0 = f2bf(v0), h1 = f2bf(v1);
      unsigned short l0 = f2bf(v0 - bf2f(h0)), l1 = f2bf(v1 - bf2f(h1));
      size_t o = ((size_t)b*196 + p)*2048 + ci0 + 2*j2;
      short2v hv; hv[0]=(short)h0; hv[1]=(short)h1;
      short2v lv; lv[0]=(short)l0; lv[1]=(short)l1;
      *(short2v*)(fhi + o) = hv;
      *(short2v*)(flo + o) = lv;
    }
  }
}

// ---------------- conv1 dense GEMM: 256co x 256g, 8 waves, counted-vmcnt 3-phase ----------------
// K=32 chunks; buffer {wh@0,wl@16384,fh@32768,fl@49152} = 64KB, dbuf 128KB, 1 blk/CU.
// Stage groups: G1={wh,fh}(4 gl16), G2={fl}(2), G3={wl}(2) issued in consumer phases.
// Phase k: ds_read -> issue G_k(it+1) -> lgkmcnt(0) -> 32 MFMA -> counted vmcnt -> barrier.
// No drain waits in steady state (vmcnt 4/6/6).
__global__ __launch_bounds__(512, 2) void k_conv1(
    const unsigned short* __restrict__ fhi, const unsigned short* __restrict__ flo,
    const unsigned short* __restrict__ wh,  const unsigned short* __restrict__ wl,
    const float* __restrict__ par,
    unsigned short* __restrict__ xhi, unsigned short* __restrict__ xlo,
    unsigned short* __restrict__ xT){
  __shared__ char lds[131072];
  char* BUF0 = lds;
  char* BUF1 = lds + 65536;
  int lin = blockIdx.x;                 // 196 blocks (no tails: 25088 = 98*256)
  int mt = lin & 1;
  int gt = lin >> 1;                    // 0..97
  int c0 = mt*256;
  size_t g0 = (size_t)gt*256;
  int t = threadIdx.x, lane = t&63, wid = t>>6;
  int wm = wid>>2, wn = wid&3;          // 2 x 4 waves; wave tile 128co x 64g
  int fq = lane>>4, fr = lane&15;
  f32x4 acc[8][4] = {};

  auto STG1 = [&](int it, char* buf){   // wh -> 0, fh -> 32768
    #pragma unroll
    for (int j=0;j<4;++j){
      int g = t + ((j&1)<<9);           // 0..1023
      int row = g>>2;
      int cs = ((g&3) ^ ((row>>1)&3))*8;
      if (j<2) gl16(wh  + (size_t)(c0+row)*2048 + it*32 + cs, buf + g*16);
      else     gl16(fhi + (g0+row)*2048 + it*32 + cs, buf + 32768 + g*16);
    }
  };
  auto STG2 = [&](int it, char* buf){   // fl -> 49152
    #pragma unroll
    for (int j=0;j<2;++j){
      int g = t + (j<<9);
      int row = g>>2;
      int cs = ((g&3) ^ ((row>>1)&3))*8;
      gl16(flo + (g0+row)*2048 + it*32 + cs, buf + 49152 + g*16);
    }
  };
  auto STG3 = [&](int it, char* buf){   // wl -> 16384
    #pragma unroll
    for (int j=0;j<2;++j){
      int g = t + (j<<9);
      int row = g>>2;
      int cs = ((g&3) ^ ((row>>1)&3))*8;
      gl16(wl + (size_t)(c0+row)*2048 + it*32 + cs, buf + 16384 + g*16);
    }
  };

  STG1(0, BUF0); STG2(0, BUF0); STG3(0, BUF0);
  asm volatile("s_waitcnt vmcnt(4)" ::: "memory");   // G1(0) done; G2,G3 outstanding
  __builtin_amdgcn_s_barrier();
  __builtin_amdgcn_sched_barrier(0);

  for (int it=0; it<64; ++it){
    char* cur = (it&1) ? BUF1 : BUF0;
    char* nxt = (it&1) ? BUF0 : BUF1;
    bool more = (it < 63);
    // ================= phase 1: hh (wh x fh) =================
    bf16x8 ah[8], bh[4];
    #pragma unroll
    for (int m=0;m<8;++m){
      int row = wm*128 + m*16 + fr;
      ah[m] = *(const bf16x8*)(cur + row*64 + ((fq*16) ^ (((row>>1)&3)<<4)));
    }
    #pragma unroll
    for (int n=0;n<4;++n){
      int row = wn*64 + n*16 + fr;
      bh[n] = *(const bf16x8*)(cur + 32768 + row*64 + ((fq*16) ^ (((row>>1)&3)<<4)));
    }
    if (more) STG1(it+1, nxt);
    asm volatile("s_waitcnt lgkmcnt(0)" ::: "memory");
    __builtin_amdgcn_sched_barrier(0);
    __builtin_amdgcn_s_setprio(1);
    #pragma unroll
    for (int n=0;n<4;++n)
      #pragma unroll
      for (int m=0;m<8;++m)
        acc[m][n] = __builtin_amdgcn_mfma_f32_16x16x32_bf16(ah[m], bh[n], acc[m][n],0,0,0);
    __builtin_amdgcn_s_setprio(0);
    if (more) { asm volatile("s_waitcnt vmcnt(6)" ::: "memory"); }   // G2(it) done
    else      { asm volatile("s_waitcnt vmcnt(2)" ::: "memory"); }
    __builtin_amdgcn_s_barrier();
    __builtin_amdgcn_sched_barrier(0);
    // ================= phase 2: hl (wh x fl) =================
    bf16x8 bl[4];
    #pragma unroll
    for (int n=0;n<4;++n){
      int row = wn*64 + n*16 + fr;
      bl[n] = *(const bf16x8*)(cur + 49152 + row*64 + ((fq*16) ^ (((row>>1)&3)<<4)));
    }
    if (more) STG2(it+1, nxt);
    asm volatile("s_waitcnt lgkmcnt(0)" ::: "memory");
    __builtin_amdgcn_sched_barrier(0);
    __builtin_amdgcn_s_setprio(1);
    #pragma unroll
    for (int n=0;n<4;++n)
      #pragma unroll
      for (int m=0;m<8;++m)
        acc[m][n] = __builtin_amdgcn_mfma_f32_16x16x32_bf16(ah[m], bl[n], acc[m][n],0,0,0);
    __builtin_amdgcn_s_setprio(0);
    if (more) { asm volatile("s_waitcnt vmcnt(6)" ::: "memory"); }   // G3(it) done
    else      { asm volatile("s_waitcnt vmcnt(0)" ::: "memory"); }
    __builtin_amdgcn_s_barrier();
    __builtin_amdgcn_sched_barrier(0);
    // ================= phase 3: lh (wl x fh) =================
    bf16x8 al[8];
    #pragma unroll
    for (int m=0;m<8;++m){
      int row = wm*128 + m*16 + fr;
      al[m] = *(const bf16x8*)(cur + 16384 + row*64 + ((fq*16) ^ (((row>>1)&3)<<4)));
    }
    if (more) STG3(it+1, nxt);
    asm volatile("s_waitcnt lgkmcnt(0)" ::: "memory");
    __builtin_amdgcn_sched_barrier(0);
    __builtin_amdgcn_s_setprio(1);
    #pragma unroll
    for (int n=0;n<4;++n)
      #pragma unroll
      for (int m=0;m<8;++m)
        acc[m][n] = __builtin_amdgcn_mfma_f32_16x16x32_bf16(al[m], bh[n], acc[m][n],0,0,0);
    __builtin_amdgcn_s_setprio(0);
    if (more) { asm volatile("s_waitcnt vmcnt(4)" ::: "memory"); }   // G1(it+1) done
    else      { asm volatile("s_waitcnt vmcnt(0)" ::: "memory"); }
    __builtin_amdgcn_s_barrier();
    __builtin_amdgcn_sched_barrier(0);
  }

  const float* s1 = par; const float* t1 = par+512;
  for (int m=0;m<8;++m){
    int cb = c0 + wm*128 + m*16 + fq*4;
    float sc[4], sh[4];
    for (int j=0;j<4;++j){ sc[j]=s1[cb+j]; sh[j]=t1[cb+j]; }
    for (int n=0;n<4;++n){
      int gg = (int)g0 + wn*64 + n*16 + fr;
      int b = gg/196, p = gg - b*196;
      unsigned short hs[4];
      for (int j=0;j<4;++j){
        float v = fmaxf(acc[m][n][j]*sc[j]+sh[j], 0.f);
        unsigned short h = f2bf(v);
        hs[j] = h;
        size_t ic = (size_t)b*512 + cb + j;
        xhi[ic*256 + p] = h;
        xlo[ic*256 + p] = f2bf(v - bf2f(h));
      }
      *(short4v*)(xT + ((size_t)b*224 + p)*512 + cb) = *(short4v*)hs;
    }
  }
}

// ---------------- xxt = x @ x^T, split precision, triangle blocks ----------------
__global__ __launch_bounds__(256) void k_xxt(const unsigned short* __restrict__ xhi,
        const unsigned short* __restrict__ xlo, float* __restrict__ xxt){
  __shared__ char lds[32768];
  char* Als = lds; char* Bls = lds + 16384;
  int lin = blockIdx.x;                       // 1280 blocks
  int sz  = (lin&7)*160 + (lin>>3);
  int b = sz/10, sub = sz - b*10;
  unsigned mtp = (3u<<18)|(2u<<16)|(2u<<14)|(1u<<12)|(1u<<10)|(1u<<8)|(0u<<6)|(0u<<4)|(0u<<2)|0u;
  unsigned ntp = (3u<<18)|(3u<<16)|(2u<<14)|(3u<<12)|(2u<<10)|(1u<<8)|(3u<<6)|(2u<<4)|(1u<<2)|0u;
  int mt = (mtp>>(2*sub))&3, nt = (ntp>>(2*sub))&3;
  int c0 = mt*128, d0 = nt*128;
  int t = threadIdx.x, lane = t&63, wid = t>>6, wm = wid&1, wn = wid>>1;
  int fq = lane>>4, fr = lane&15;
  f32x4 acc[4][4] = {};
  for (int it=0; it<12; ++it){
    int seg = it>>2, kk0 = (it&3)*64;
    const unsigned short* As = (seg<2) ? xhi : xlo;
    const unsigned short* Bs = (seg==1) ? xlo : xhi;
    __syncthreads();
    #pragma unroll
    for (int r=0;r<4;++r){
      int L = r*256 + t;
      int row = L>>3, cs = ((L&7)^(row&7))*8;
      gl16(As + ((size_t)b*512 + c0 + row)*256 + kk0 + cs, Als + L*16);
      gl16(Bs + ((size_t)b*512 + d0 + row)*256 + kk0 + cs, Bls + L*16);
    }
    __syncthreads();
    #pragma unroll
    for (int ks=0; ks<2; ++ks){
      int kb = ks*64 + fq*16;
      bf16x8 af[4];
      #pragma unroll
      for (int m=0;m<4;++m){
        int row = wm*64 + m*16 + fr;
        af[m] = *(const bf16x8*)(Als + row*128 + (kb ^ ((row&7)<<4)));
      }
      #pragma unroll
      for (int n=0;n<4;++n){
        int row = wn*64 + n*16 + fr;
        bf16x8 bff = *(const bf16x8*)(Bls + row*128 + (kb ^ ((row&7)<<4)));
        #pragma unroll
        for (int m=0;m<4;++m)
          acc[m][n] = __builtin_amdgcn_mfma_f32_16x16x32_bf16(af[m], bff, acc[m][n],0,0,0);
      }
    }
  }
  for (int m=0;m<4;++m){
    int cb = c0 + wm*64 + m*16 + fq*4;
    for (int n=0;n<4;++n){
      int d = d0 + wn*64 + n*16 + fr;
      *(float4*)(xxt + ((size_t)b*512 + d)*512 + cb) = *(float4*)&acc[m][n];
    }
  }
  if (mt != nt){
    for (int m=0;m<4;++m){
      int cb = c0 + wm*64 + m*16 + fq*4;
      for (int n=0;n<4;++n){
        int d = d0 + wn*64 + n*16 + fr;
        for (int jj=0;jj<4;++jj)
          xxt[((size_t)b*512 + cb + jj)*512 + d] = acc[m][n][jj];
      }
    }
  }
}

// ---------------- softmax(-xxt) rows -> a (bf16) ----------------
__global__ __launch_bounds__(256) void k_softmax(const float* __restrict__ xxt, unsigned short* __restrict__ amat){
  int row = blockIdx.x*4 + (threadIdx.x>>6);
  int lane = threadIdx.x & 63;
  const float* src = xxt + (size_t)row*512 + lane*8;
  float4 v0 = *(const float4*)src;
  float4 v1 = *(const float4*)(src+4);
  float mn = fminf(fminf(fminf(v0.x,v0.y),fminf(v0.z,v0.w)),
                   fminf(fminf(v1.x,v1.y),fminf(v1.z,v1.w)));
  for (int m=32; m; m>>=1) mn = fminf(mn, __shfl_xor(mn, m, 64));
  float e[8];
  e[0]=__expf(mn-v0.x); e[1]=__expf(mn-v0.y); e[2]=__expf(mn-v0.z); e[3]=__expf(mn-v0.w);
  e[4]=__expf(mn-v1.x); e[5]=__expf(mn-v1.y); e[6]=__expf(mn-v1.z); e[7]=__expf(mn-v1.w);
  float s = e[0]+e[1]+e[2]+e[3]+e[4]+e[5]+e[6]+e[7];
  for (int m=32; m; m>>=1) s += __shfl_xor(s, m, 64);
  float inv = 1.f/s;
  short4v p0, p1;
  for (int q=0;q<4;++q) p0[q] = (short)f2bf(e[q]*inv);
  for (int q=0;q<4;++q) p1[q] = (short)f2bf(e[4+q]*inv);
  unsigned short* dst = amat + (size_t)row*512 + lane*8;
  *(short4v*)dst = p0;
  *(short4v*)(dst+4) = p1;
}

// ---------------- PV: y = a @ x -> ypad [b][ci0b 8][prow 256][cio 64]; also zero borders ----------------
__global__ __launch_bounds__(256) void k_pv(const unsigned short* __restrict__ amat,
        const unsigned short* __restrict__ xT, unsigned short* __restrict__ ypad){
  __shared__ char lds[30720];
  char* Als = lds; char* Bls = lds + 16384;
  int lin = blockIdx.x, per = gridDim.x>>3;
  int sz  = (lin&7)*per + (lin>>3);
  int b = sz>>3, sub = sz&7, mt = sub>>1, nt = sub&1;
  int c0 = mt*128, n0 = nt*112;
  int t = threadIdx.x, lane = t&63, wid = t>>6;
  int fq = lane>>4, fr = lane&15;
  {
    int r = t;
    int hi = r>>4, lo2 = r&15;
    if (hi==0||hi==15||lo2==0||lo2==15){
      float4 z = {0.f,0.f,0.f,0.f};
      float4* pz = (float4*)(ypad + (((size_t)b*8 + sub)*256 + r)*64);
      #pragma unroll
      for (int q=0;q<8;++q) pz[q] = z;
    }
  }
  f32x4 acc[2][7] = {};
  for (int it=0; it<8; ++it){
    int k0 = it*64;
    __syncthreads();
    #pragma unroll
    for (int r=0;r<4;++r){
      int L = r*256 + t;
      int row = L>>3, cs = ((L&7)^(row&7))*8;
      gl16(amat + ((size_t)b*512 + c0 + row)*512 + k0 + cs, Als + L*16);
    }
    #pragma unroll
    for (int r=0;r<4;++r){
      int L = r*256 + t;
      if (L < 896){
        int row = L>>3, cs = ((L&7)^(row&7))*8;
        gl16(xT + ((size_t)b*224 + n0 + row)*512 + k0 + cs, Bls + L*16);
      }
    }
    __syncthreads();
    #pragma unroll
    for (int ks=0; ks<2; ++ks){
      int kb = ks*64 + fq*16;
      bf16x8 af[2];
      #pragma unroll
      for (int m=0;m<2;++m){
        int row = wid*32 + m*16 + fr;
        af[m] = *(const bf16x8*)(Als + row*128 + (kb ^ ((row&7)<<4)));
      }
      #pragma unroll
      for (int n=0;n<7;++n){
        int row = n*16 + fr;
        bf16x8 bff = *(const bf16x8*)(Bls + row*128 + (kb ^ ((row&7)<<4)));
        #pragma unroll
        for (int m=0;m<2;++m)
          acc[m][n] = __builtin_amdgcn_mfma_f32_16x16x32_bf16(af[m], bff, acc[m][n],0,0,0);
      }
    }
  }
  for (int m=0;m<2;++m){
    int cb = c0 + wid*32 + m*16 + fq*4;
    int ci0b = cb>>6, cio = cb&63;
    for (int n=0;n<7;++n){
      int p = n0 + n*16 + fr;
      if (p < 196){
        int hh = p/14, wwp = p - hh*14;
        int prow = (hh+1)*16 + (wwp+1);
        short4v pk;
        for (int j=0;j<4;++j) pk[j] = (short)f2bf(acc[m][n][j]);
        *(short4v*)(ypad + (((size_t)b*8 + ci0b)*256 + prow)*64 + cio) = pk;
      }
    }
  }
}

// ---------------- conv3 implicit GEMM + BN2 + ReLU + avgpool -> zbar (sum) ----------------
// K-split wave tile: wave = 64co x 7rows x 1 ks-half (8 waves = 2wm x 2wn x 2wks).
__global__ __launch_bounds__(512, 2) void k_conv3(const unsigned short* __restrict__ ypad,
        const unsigned short* __restrict__ w3c, const float* __restrict__ par,
        float* __restrict__ zbar){
  __shared__ char lds[65536];
  char* WIN = lds;
  char* AB0 = lds + 32768;
  char* AB1 = lds + 49152;
  int bx = blockIdx.x;             // 512 blocks
  int xcd = bx&7, jj2 = bx>>3;
  int b = xcd*16 + (jj2>>2), cot = jj2&3;
  int c0 = cot*128;
  int t = threadIdx.x, lane = t&63, w = t>>6;
  int wm = w>>2, wn = (w>>1)&1, wks = w&1;
  int fq = lane>>4, fr = lane&15;
  int frB = (fr<14) ? fr : 13;
  bool pok = (fr<14);
  f32x4 acc[4][7] = {};
  for (int ci0=0; ci0<8; ++ci0){
    const unsigned short* wsrc = ypad + ((size_t)(b*8 + ci0)*256)*64;
    #pragma unroll
    for (int r=0;r<4;++r){
      int L = r*512 + t;
      int row = L>>3, cs = ((L&7)^(row&7))*8;
      gl16(wsrc + row*64 + cs, WIN + L*16);
    }
    {
      const unsigned short* asrc = w3c + ((size_t)(ci0*9 + 0)*512 + c0)*64;
      #pragma unroll
      for (int r=0;r<2;++r){
        int L = r*512 + t;
        int row = L>>3, cs = ((L&7)^(row&7))*8;
        gl16(asrc + row*64 + cs, AB0 + L*16);
      }
    }
    __syncthreads();
    for (int tap=0; tap<9; ++tap){
      char* Acur = (tap&1) ? AB1 : AB0;
      char* Anxt = (tap&1) ? AB0 : AB1;
      if (tap < 8){
        const unsigned short* asrc = w3c + ((size_t)(ci0*9 + tap+1)*512 + c0)*64;
        #pragma unroll
        for (int r=0;r<2;++r){
          int L = r*512 + t;
          int row = L>>3, cs = ((L&7)^(row&7))*8;
          gl16(asrc + row*64 + cs, Anxt + L*16);
        }
      }
      int kh = tap/3, kw = tap - kh*3;
      bf16x8 ah[4];
      #pragma unroll
      for (int m=0;m<4;++m){
        int row = wm*64 + m*16 + fr;
        ah[m] = *(const bf16x8*)(Acur + row*128 + (((wks*4+fq)^(row&7))<<4));
      }
      int col = frB + kw;
      __builtin_amdgcn_s_setprio(1);
      #pragma unroll
      for (int n=0;n<7;++n){
        int prow = (wn*7 + n + kh)*16 + col;
        bf16x8 bf = *(const bf16x8*)(WIN + prow*128 + (((wks*4+fq)^(prow&7))<<4));
        #pragma unroll
        for (int m=0;m<4;++m)
          acc[m][n] = __builtin_amdgcn_mfma_f32_16x16x32_bf16(ah[m], bf, acc[m][n],0,0,0);
      }
      __builtin_amdgcn_s_setprio(0);
      __syncthreads();
    }
  }
  #pragma unroll
  for (int half=0; half<2; ++half){
    if (wks){
      #pragma unroll
      for (int m2=0;m2<2;++m2)
        #pragma unroll
        for (int n=0;n<7;++n)
          *(f32x4*)(lds + (((size_t)((wm*2+wn)*14 + m2*7 + n))*64 + lane)*16) = acc[half*2+m2][n];
    }
    __syncthreads();
    if (!wks){
      #pragma unroll
      for (int m2=0;m2<2;++m2)
        #pragma unroll
        for (int n=0;n<7;++n){
          f32x4 o = *(const f32x4*)(lds + (((size_t)((wm*2+wn)*14 + m2*7 + n))*64 + lane)*16);
          acc[half*2+m2][n] += o;
        }
    }
    __syncthreads();
  }
  const float* s2 = par+1024; const float* t2 = par+1536;
  float ps[4][4];
  if (!wks){
    #pragma unroll
    for (int m=0;m<4;++m){
      int cb = c0 + wm*64 + m*16 + fq*4;
      #pragma unroll
      for (int j=0;j<4;++j){
        float sc = s2[cb+j], sh = t2[cb+j];
        float s = 0.f;
        #pragma unroll
        for (int n=0;n<7;++n)
          s += fmaxf(acc[m][n][j]*sc + sh, 0.f);
        ps[m][j] = pok ? s : 0.f;
      }
    }
    #pragma unroll
    for (int off=1; off<16; off<<=1)
      #pragma unroll
      for (int m=0;m<4;++m)
        #pragma unroll
        for (int j=0;j<4;++j)
          ps[m][j] += __shfl_xor(ps[m][j], off, 64);
  }
  float* part = (float*)lds;
  if (!wks && fr == 0){
    #pragma unroll
    for (int m=0;m<4;++m)
      #pragma unroll
      for (int j=0;j<4;++j)
        part[wn*128 + wm*64 + m*16 + fq*4 + j] = ps[m][j];
  }
  __syncthreads();
  if (t < 128)
    zbar[(size_t)b*512 + c0 + t] = part[t] + part[128 + t];
}

// ---------------- fc1(relu) + fc2 ----------------
__global__ __launch_bounds__(256) void k_fc(const float* __restrict__ zbar,
        const float* __restrict__ fc1T, const float* __restrict__ fc1b,
        const float* __restrict__ fc2T, const float* __restrict__ fc2b,
        float* __restrict__ out){
  __shared__ float zb[512];
  __shared__ float hl[200];
  int b = blockIdx.x, t = threadIdx.x;
  zb[t]     = zbar[(size_t)b*512 + t]       * (1.f/196.f);
  zb[t+256] = zbar[(size_t)b*512 + t + 256] * (1.f/196.f);
  __syncthreads();
  if (t < 200){
    float acc = fc1b[t];
    for (int k=0;k<512;++k) acc += zb[k]*fc1T[k*200+t];
    hl[t] = fmaxf(acc, 0.f);
  }
  __syncthreads();
  if (t < 200){
    float acc = fc2b[t];
    for (int k=0;k<200;++k) acc += hl[k]*fc2T[k*200+t];
    out[(size_t)b*200 + t] = acc;
  }
}

extern "C" void kernel_launch(void* const* d_in, const int* in_sizes, int n_in,
                              void* d_out, int out_size, void* d_ws, size_t ws_size,
                              hipStream_t stream) {
  const float* feature  = (const float*)d_in[0];
  const float* w_reduce = (const float*)d_in[1];
  const float* b_reduce = (const float*)d_in[2];
  const float* g1  = (const float*)d_in[3];
  const float* be1 = (const float*)d_in[4];
  const float* m1  = (const float*)d_in[5];
  const float* v1  = (const float*)d_in[6];
  const float* w3  = (const float*)d_in[7];
  const float* b3  = (const float*)d_in[8];
  const float* g2  = (const float*)d_in[9];
  const float* be2 = (const float*)d_in[10];
  const float* m2  = (const float*)d_in[11];
  const float* v2  = (const float*)d_in[12];
  const float* fc1w = (const float*)d_in[13];
  const float* fc1b = (const float*)d_in[14];
  const float* fc2w = (const float*)d_in[15];
  const float* fc2b = (const float*)d_in[16];

  char* ws = (char*)d_ws;
  unsigned short* fhi  = (unsigned short*)(ws + O_FHI);
  unsigned short* flo  = (unsigned short*)(ws + O_FLO);
  float*          xxt  = (float*)(ws + O_FHI);      // aliases fhi (dead after conv1)
  unsigned short* xhi  = (unsigned short*)(ws + O_XHI);
  unsigned short* xlo  = (unsigned short*)(ws + O_XLO);
  unsigned short* ypad = (unsigned short*)(ws + O_XLO);  // aliases xlo (dead after xxt)
  unsigned short* xT   = (unsigned short*)(ws + O_XT);
  unsigned short* amat = (unsigned short*)(ws + O_AMAT);
  unsigned short* wh   = (unsigned short*)(ws + O_WH);
  unsigned short* wl   = (unsigned short*)(ws + O_WL);
  unsigned short* w3c  = (unsigned short*)(ws + O_W3B);
  float* par  = (float*)(ws + O_PAR);
  float* fc1T = (float*)(ws + O_FC1T);
  float* fc2T = (float*)(ws + O_FC2T);
  float* zbar = (float*)(ws + O_ZBAR);

  k_prep<<<14127, 256, 0, stream>>>(w_reduce, wh, wl, w3, w3c,
      fc1w, fc1T, fc2w, fc2T,
      b_reduce, g1, be1, m1, v1, b3, g2, be2, m2, v2, par, xhi, xlo);

  k_featT<<<dim3(7,32,128), 256, 0, stream>>>(feature, fhi, flo);
  k_conv1<<<196, 512, 0, stream>>>(fhi, flo, wh, wl, par, xhi, xlo, xT);

  k_xxt<<<1280, 256, 0, stream>>>(xhi, xlo, xxt);
  k_softmax<<<16384, 256, 0, stream>>>(xxt, amat);

  k_pv<<<1024, 256, 0, stream>>>(amat, xT, ypad);   // also zeroes ypad borders
  k_conv3<<<512, 512, 0, stream>>>(ypad, w3c, par, zbar);
  k_fc<<<128, 256, 0, stream>>>(zbar, fc1T, fc1b, fc2T, fc2b, (float*)d_out);
}

// Round 12
// 586.271 us; speedup vs baseline: 1.0723x; 1.0723x over previous
//
#include <hip/hip_runtime.h>

typedef __attribute__((ext_vector_type(8))) short bf16x8;
typedef __attribute__((ext_vector_type(4))) float f32x4;
typedef __attribute__((ext_vector_type(4))) short short4v;
typedef __attribute__((ext_vector_type(2))) short short2v;

__device__ __forceinline__ unsigned short f2bf(float x){
  unsigned u = __float_as_uint(x);
  return (unsigned short)((u + 0x7FFFu + ((u>>16)&1u)) >> 16);
}
__device__ __forceinline__ float bf2f(unsigned short b){
  return __uint_as_float(((unsigned)b)<<16);
}

typedef const __attribute__((address_space(1))) void* gas_t;
typedef __attribute__((address_space(3))) void* las_t;
__device__ __forceinline__ void gl16(const void* g, void* l){
  __builtin_amdgcn_global_load_lds((gas_t)g, (las_t)l, 16, 0, 0);
}

// ---------------- workspace layout (bytes), ws_size ~784 MiB ----------------
static constexpr size_t O_FHI  = 0;              // fhi bf16 [25088][2048] (later xxt f32)
static constexpr size_t O_FLO  = 102760448;      // flo bf16 [25088][2048]
static constexpr size_t O_XHI  = 205520896;      // x_hi bf16 [128][512][256]
static constexpr size_t O_XLO  = 239075328;      // x_lo bf16 (later ypad [b][8][256][64])
static constexpr size_t O_XT   = 272629760;      // xT bf16 [128][224][512]
static constexpr size_t O_AMAT = 301989888;      // a bf16 [128][512][512]
static constexpr size_t O_WH   = 369098752;      // wh bf16 [512][2048]
static constexpr size_t O_WL   = 371195904;      // wl
static constexpr size_t O_W3B  = 373293056;      // w3c bf16 [8][9][512][64]
static constexpr size_t O_PAR  = 378011648;      // s1,t1,s2,t2
static constexpr size_t O_FC1T = 378019840;      // fc1T f32 [512][200]
static constexpr size_t O_FC2T = 378429440;      // fc2T f32 [200][200]
static constexpr size_t O_ZBAR = 378589440;      // zbar f32 [128][512] (sum)

// ---------------- fused prep kernel (ranges over blockIdx) ----------------
__global__ __launch_bounds__(256) void k_prep(
    const float* wr, unsigned short* wh, unsigned short* wl,
    const float* w3, unsigned short* w3c,
    const float* fc1w, float* fc1T, const float* fc2w, float* fc2T,
    const float* br, const float* g1, const float* be1, const float* m1, const float* v1,
    const float* b3, const float* g2, const float* be2, const float* m2, const float* v2,
    float* par, unsigned short* xhi, unsigned short* xlo){
  int blk = blockIdx.x, t = threadIdx.x;
  if (blk < 4096){                       // wh/wl split: 512x2048
    int idx = blk*256 + t;
    int c = idx >> 11, k = idx & 2047;
    float v = wr[(size_t)c*2048 + k];
    unsigned short h = f2bf(v);
    wh[(size_t)c*2048+k] = h; wl[(size_t)c*2048+k] = f2bf(v - bf2f(h));
  } else if (blk < 13312){               // w3c repack: 512x4608
    int i = (blk-4096)*256 + t;
    int co = i / 4608, k = i - co*4608;
    int ci0b = k / 576, r2 = k - ci0b*576;
    int tap = r2 >> 6, cio = r2 & 63;
    w3c[(((size_t)ci0b*9+tap)*512+co)*64+cio] =
        f2bf(w3[((size_t)co*512 + ci0b*64+cio)*9 + tap]);
  } else if (blk < 13712){               // fc1T
    int i = (blk-13312)*256 + t;
    int k = i/200, j = i - k*200;
    fc1T[i] = fc1w[j*512+k];
  } else if (blk < 13869){               // fc2T
    int i = (blk-13712)*256 + t;
    if (i < 40000){ int k = i/200, j = i - k*200; fc2T[i] = fc2w[j*200+k]; }
  } else if (blk < 13871){               // BN params
    int c = (blk-13869)*256 + t;
    if (c < 512){
      float s1 = g1[c]*rsqrtf(v1[c]+1e-5f);
      par[c] = s1; par[512+c] = (br[c]-m1[c])*s1 + be1[c];
      float s2 = g2[c]*rsqrtf(v2[c]+1e-5f);
      par[1024+c] = s2; par[1536+c] = (b3[c]-m2[c])*s2 + be2[c];
    }
  } else {                               // zero pad cols [192,256) of xhi/xlo
    int rr = (blk-13871)*256 + t;        // 65536 rows
    float4 z = {0.f,0.f,0.f,0.f};
    float4* a = (float4*)(xhi + (size_t)rr*256 + 192);
    float4* bq = (float4*)(xlo + (size_t)rr*256 + 192);
    #pragma unroll
    for (int q=0;q<8;++q){ a[q]=z; bq[q]=z; }
  }
}

// transpose+split feature -> dense fhi/flo bf16 [b*196+p][2048], ushort2 writes
__global__ __launch_bounds__(256) void k_featT(const float* __restrict__ feat,
        unsigned short* __restrict__ fhi, unsigned short* __restrict__ flo){
  __shared__ float tile[64][33];
  int b = blockIdx.z;
  int ci0 = blockIdx.y*64, p0 = blockIdx.x*32;
  int t = threadIdx.x;
  int j = t & 31, i0 = t >> 5;
  for (int rep=0; rep<8; ++rep){
    int i = rep*8 + i0;
    int p = p0 + j;
    tile[i][j] = (p<196) ? feat[((size_t)b*2048 + ci0 + i)*196 + p] : 0.f;
  }
  __syncthreads();
  int j2 = t & 31;
  int jj0 = t >> 5;
  for (int rep=0; rep<4; ++rep){
    int jj = rep*8 + jj0;
    int p = p0 + jj;
    if (p < 196){
      float v0 = tile[2*j2][jj], v1 = tile[2*j2+1][jj];
      unsigned short h0 = f2bf(v0), h1 = f2bf(v1);
      unsigned short l0 = f2bf(v0 - bf2f(h0)), l1 = f2bf(v1 - bf2f(h1));
      size_t o = ((size_t)b*196 + p)*2048 + ci0 + 2*j2;
      short2v hv; hv[0]=(short)h0; hv[1]=(short)h1;
      short2v lv; lv[0]=(short)l0; lv[1]=(short)l1;
      *(short2v*)(fhi + o) = hv;
      *(short2v*)(flo + o) = lv;
    }
  }
}

// ---------------- conv1 dense GEMM (R9 champion: 128x128, 4 waves, 2-phase, 2 blk/CU) ----------------
__global__ __launch_bounds__(256, 2) void k_conv1(
    const unsigned short* __restrict__ fhi, const unsigned short* __restrict__ flo,
    const unsigned short* __restrict__ wh,  const unsigned short* __restrict__ wl,
    const float* __restrict__ par,
    unsigned short* __restrict__ xhi, unsigned short* __restrict__ xlo,
    unsigned short* __restrict__ xT){
  __shared__ char lds[65536];
  char* BUF0 = lds;
  char* BUF1 = lds + 32768;
  int lin = blockIdx.x;                       // 784 blocks = 8 XCD x 98
  int sz  = (lin&7)*98 + (lin>>3);
  int mt = sz&3;
  int gt = sz>>2;
  int c0 = mt*128;
  size_t g0 = (size_t)gt*128;
  int t = threadIdx.x, lane = t&63, wid = t>>6, wm = wid&1, wn = wid>>1;
  int fq = lane>>4, fr = lane&15;
  f32x4 acc[4][4] = {};

  auto STAGE = [&](int it, char* buf){
    #pragma unroll
    for (int jj=0; jj<8; ++jj){
      int arr = jj>>1;
      int g = t + ((jj&1)<<8);                // 0..511
      int row = g>>2;
      int cs = ((g&3) ^ ((row>>1)&3))*8;
      const unsigned short* src;
      if (arr==0)      src = wh  + (size_t)(c0+row)*2048 + it*32 + cs;
      else if (arr==1) src = wl  + (size_t)(c0+row)*2048 + it*32 + cs;
      else if (arr==2) src = fhi + (g0+row)*2048 + it*32 + cs;
      else             src = flo + (g0+row)*2048 + it*32 + cs;
      gl16(src, buf + arr*8192 + g*16);
    }
  };

  STAGE(0, BUF0);
  asm volatile("s_waitcnt vmcnt(0)" ::: "memory");
  __builtin_amdgcn_s_barrier();
  __builtin_amdgcn_sched_barrier(0);

  for (int it=0; it<64; ++it){
    char* cur = (it&1) ? BUF1 : BUF0;
    char* nxt = (it&1) ? BUF0 : BUF1;
    if (it < 63) STAGE(it+1, nxt);
    bf16x8 ah[4], al[4], bh[4], bl[4];
    #pragma unroll
    for (int m=0;m<4;++m){
      int row = wm*64 + m*16 + fr;
      int off = row*64 + ((fq*16) ^ (((row>>1)&3)<<4));
      ah[m] = *(const bf16x8*)(cur + off);
      al[m] = *(const bf16x8*)(cur + 8192 + off);
    }
    #pragma unroll
    for (int n=0;n<4;++n){
      int row = wn*64 + n*16 + fr;
      int off = row*64 + ((fq*16) ^ (((row>>1)&3)<<4));
      bh[n] = *(const bf16x8*)(cur + 16384 + off);
      bl[n] = *(const bf16x8*)(cur + 24576 + off);
    }
    __builtin_amdgcn_s_setprio(1);
    #pragma unroll
    for (int n=0;n<4;++n)
      #pragma unroll
      for (int m=0;m<4;++m){
        acc[m][n] = __builtin_amdgcn_mfma_f32_16x16x32_bf16(ah[m], bh[n], acc[m][n],0,0,0);
        acc[m][n] = __builtin_amdgcn_mfma_f32_16x16x32_bf16(ah[m], bl[n], acc[m][n],0,0,0);
        acc[m][n] = __builtin_amdgcn_mfma_f32_16x16x32_bf16(al[m], bh[n], acc[m][n],0,0,0);
      }
    __builtin_amdgcn_s_setprio(0);
    asm volatile("s_waitcnt vmcnt(0)" ::: "memory");
    __builtin_amdgcn_s_barrier();
    __builtin_amdgcn_sched_barrier(0);
  }

  const float* s1 = par; const float* t1 = par+512;
  for (int m=0;m<4;++m){
    int cb = c0 + wm*64 + m*16 + fq*4;
    float sc[4], sh[4];
    for (int j=0;j<4;++j){ sc[j]=s1[cb+j]; sh[j]=t1[cb+j]; }
    for (int n=0;n<4;++n){
      int gg = (int)g0 + wn*64 + n*16 + fr;
      int b = gg/196, p = gg - b*196;
      unsigned short hs[4];
      for (int j=0;j<4;++j){
        float v = fmaxf(acc[m][n][j]*sc[j]+sh[j], 0.f);
        unsigned short h = f2bf(v);
        hs[j] = h;
        size_t ic = (size_t)b*512 + cb + j;
        xhi[ic*256 + p] = h;
        xlo[ic*256 + p] = f2bf(v - bf2f(h));
      }
      *(short4v*)(xT + ((size_t)b*224 + p)*512 + cb) = *(short4v*)hs;
    }
  }
}

// ---------------- xxt = x @ x^T, split precision, triangle blocks ----------------
__global__ __launch_bounds__(256) void k_xxt(const unsigned short* __restrict__ xhi,
        const unsigned short* __restrict__ xlo, float* __restrict__ xxt){
  __shared__ char lds[32768];
  char* Als = lds; char* Bls = lds + 16384;
  int lin = blockIdx.x;                       // 1280 blocks
  int sz  = (lin&7)*160 + (lin>>3);
  int b = sz/10, sub = sz - b*10;
  unsigned mtp = (3u<<18)|(2u<<16)|(2u<<14)|(1u<<12)|(1u<<10)|(1u<<8)|(0u<<6)|(0u<<4)|(0u<<2)|0u;
  unsigned ntp = (3u<<18)|(3u<<16)|(2u<<14)|(3u<<12)|(2u<<10)|(1u<<8)|(3u<<6)|(2u<<4)|(1u<<2)|0u;
  int mt = (mtp>>(2*sub))&3, nt = (ntp>>(2*sub))&3;
  int c0 = mt*128, d0 = nt*128;
  int t = threadIdx.x, lane = t&63, wid = t>>6, wm = wid&1, wn = wid>>1;
  int fq = lane>>4, fr = lane&15;
  f32x4 acc[4][4] = {};
  for (int it=0; it<12; ++it){
    int seg = it>>2, kk0 = (it&3)*64;
    const unsigned short* As = (seg<2) ? xhi : xlo;
    const unsigned short* Bs = (seg==1) ? xlo : xhi;
    __syncthreads();
    #pragma unroll
    for (int r=0;r<4;++r){
      int L = r*256 + t;
      int row = L>>3, cs = ((L&7)^(row&7))*8;
      gl16(As + ((size_t)b*512 + c0 + row)*256 + kk0 + cs, Als + L*16);
      gl16(Bs + ((size_t)b*512 + d0 + row)*256 + kk0 + cs, Bls + L*16);
    }
    __syncthreads();
    #pragma unroll
    for (int ks=0; ks<2; ++ks){
      int kb = ks*64 + fq*16;
      bf16x8 af[4];
      #pragma unroll
      for (int m=0;m<4;++m){
        int row = wm*64 + m*16 + fr;
        af[m] = *(const bf16x8*)(Als + row*128 + (kb ^ ((row&7)<<4)));
      }
      #pragma unroll
      for (int n=0;n<4;++n){
        int row = wn*64 + n*16 + fr;
        bf16x8 bff = *(const bf16x8*)(Bls + row*128 + (kb ^ ((row&7)<<4)));
        #pragma unroll
        for (int m=0;m<4;++m)
          acc[m][n] = __builtin_amdgcn_mfma_f32_16x16x32_bf16(af[m], bff, acc[m][n],0,0,0);
      }
    }
  }
  for (int m=0;m<4;++m){
    int cb = c0 + wm*64 + m*16 + fq*4;
    for (int n=0;n<4;++n){
      int d = d0 + wn*64 + n*16 + fr;
      *(float4*)(xxt + ((size_t)b*512 + d)*512 + cb) = *(float4*)&acc[m][n];
    }
  }
  if (mt != nt){
    for (int m=0;m<4;++m){
      int cb = c0 + wm*64 + m*16 + fq*4;
      for (int n=0;n<4;++n){
        int d = d0 + wn*64 + n*16 + fr;
        for (int jj=0;jj<4;++jj)
          xxt[((size_t)b*512 + cb + jj)*512 + d] = acc[m][n][jj];
      }
    }
  }
}

// ---------------- softmax(-xxt) rows -> a (bf16) ----------------
__global__ __launch_bounds__(256) void k_softmax(const float* __restrict__ xxt, unsigned short* __restrict__ amat){
  int row = blockIdx.x*4 + (threadIdx.x>>6);
  int lane = threadIdx.x & 63;
  const float* src = xxt + (size_t)row*512 + lane*8;
  float4 v0 = *(const float4*)src;
  float4 v1 = *(const float4*)(src+4);
  float mn = fminf(fminf(fminf(v0.x,v0.y),fminf(v0.z,v0.w)),
                   fminf(fminf(v1.x,v1.y),fminf(v1.z,v1.w)));
  for (int m=32; m; m>>=1) mn = fminf(mn, __shfl_xor(mn, m, 64));
  float e[8];
  e[0]=__expf(mn-v0.x); e[1]=__expf(mn-v0.y); e[2]=__expf(mn-v0.z); e[3]=__expf(mn-v0.w);
  e[4]=__expf(mn-v1.x); e[5]=__expf(mn-v1.y); e[6]=__expf(mn-v1.z); e[7]=__expf(mn-v1.w);
  float s = e[0]+e[1]+e[2]+e[3]+e[4]+e[5]+e[6]+e[7];
  for (int m=32; m; m>>=1) s += __shfl_xor(s, m, 64);
  float inv = 1.f/s;
  short4v p0, p1;
  for (int q=0;q<4;++q) p0[q] = (short)f2bf(e[q]*inv);
  for (int q=0;q<4;++q) p1[q] = (short)f2bf(e[4+q]*inv);
  unsigned short* dst = amat + (size_t)row*512 + lane*8;
  *(short4v*)dst = p0;
  *(short4v*)(dst+4) = p1;
}

// ---------------- PV: y = a @ x -> ypad [b][ci0b 8][prow 256][cio 64]; also zero borders ----------------
__global__ __launch_bounds__(256) void k_pv(const unsigned short* __restrict__ amat,
        const unsigned short* __restrict__ xT, unsigned short* __restrict__ ypad){
  __shared__ char lds[30720];
  char* Als = lds; char* Bls = lds + 16384;
  int lin = blockIdx.x, per = gridDim.x>>3;
  int sz  = (lin&7)*per + (lin>>3);
  int b = sz>>3, sub = sz&7, mt = sub>>1, nt = sub&1;
  int c0 = mt*128, n0 = nt*112;
  int t = threadIdx.x, lane = t&63, wid = t>>6;
  int fq = lane>>4, fr = lane&15;
  {
    int r = t;
    int hi = r>>4, lo2 = r&15;
    if (hi==0||hi==15||lo2==0||lo2==15){
      float4 z = {0.f,0.f,0.f,0.f};
      float4* pz = (float4*)(ypad + (((size_t)b*8 + sub)*256 + r)*64);
      #pragma unroll
      for (int q=0;q<8;++q) pz[q] = z;
    }
  }
  f32x4 acc[2][7] = {};
  for (int it=0; it<8; ++it){
    int k0 = it*64;
    __syncthreads();
    #pragma unroll
    for (int r=0;r<4;++r){
      int L = r*256 + t;
      int row = L>>3, cs = ((L&7)^(row&7))*8;
      gl16(amat + ((size_t)b*512 + c0 + row)*512 + k0 + cs, Als + L*16);
    }
    #pragma unroll
    for (int r=0;r<4;++r){
      int L = r*256 + t;
      if (L < 896){
        int row = L>>3, cs = ((L&7)^(row&7))*8;
        gl16(xT + ((size_t)b*224 + n0 + row)*512 + k0 + cs, Bls + L*16);
      }
    }
    __syncthreads();
    #pragma unroll
    for (int ks=0; ks<2; ++ks){
      int kb = ks*64 + fq*16;
      bf16x8 af[2];
      #pragma unroll
      for (int m=0;m<2;++m){
        int row = wid*32 + m*16 + fr;
        af[m] = *(const bf16x8*)(Als + row*128 + (kb ^ ((row&7)<<4)));
      }
      #pragma unroll
      for (int n=0;n<7;++n){
        int row = n*16 + fr;
        bf16x8 bff = *(const bf16x8*)(Bls + row*128 + (kb ^ ((row&7)<<4)));
        #pragma unroll
        for (int m=0;m<2;++m)
          acc[m][n] = __builtin_amdgcn_mfma_f32_16x16x32_bf16(af[m], bff, acc[m][n],0,0,0);
      }
    }
  }
  for (int m=0;m<2;++m){
    int cb = c0 + wid*32 + m*16 + fq*4;
    int ci0b = cb>>6, cio = cb&63;
    for (int n=0;n<7;++n){
      int p = n0 + n*16 + fr;
      if (p < 196){
        int hh = p/14, wwp = p - hh*14;
        int prow = (hh+1)*16 + (wwp+1);
        short4v pk;
        for (int j=0;j<4;++j) pk[j] = (short)f2bf(acc[m][n][j]);
        *(short4v*)(ypad + (((size_t)b*8 + ci0b)*256 + prow)*64 + cio) = pk;
      }
    }
  }
}

// ---------------- conv3 implicit GEMM + BN2 + ReLU + avgpool -> zbar (sum) ----------------
// K-split wave tile (R9) + 3-buffer A with counted vmcnt(2) tap barriers:
// A(T+2) issued during tap T; barrier_T waits vmcnt(2) (A(T+1) complete, A(T+2) in flight).
// Full vmcnt(0) only at ci0 heads (WIN staging) and the last two taps.
__global__ __launch_bounds__(512, 2) void k_conv3(const unsigned short* __restrict__ ypad,
        const unsigned short* __restrict__ w3c, const float* __restrict__ par,
        float* __restrict__ zbar){
  __shared__ char lds[81920];
  char* WIN = lds;                 // [256][64] bf16, swizzled (32 KB)
  char* AB[3] = { lds + 32768, lds + 49152, lds + 65536 };   // 3 x 16 KB
  int bx = blockIdx.x;             // 512 blocks
  int xcd = bx&7, jj2 = bx>>3;
  int b = xcd*16 + (jj2>>2), cot = jj2&3;
  int c0 = cot*128;
  int t = threadIdx.x, lane = t&63, w = t>>6;
  int wm = w>>2, wn = (w>>1)&1, wks = w&1;
  int fq = lane>>4, fr = lane&15;
  int frB = (fr<14) ? fr : 13;
  bool pok = (fr<14);
  f32x4 acc[4][7] = {};

  auto STG_A = [&](int T){         // A chunk T -> AB[T%3]
    const unsigned short* asrc = w3c + ((size_t)T*512 + c0)*64;
    char* buf = AB[T%3];
    #pragma unroll
    for (int r=0;r<2;++r){
      int L = r*512 + t;
      int row = L>>3, cs = ((L&7)^(row&7))*8;
      gl16(asrc + row*64 + cs, buf + L*16);
    }
  };

  // prologue: A(0), A(1) in flight; WIN(0) staged at head below
  STG_A(0);
  STG_A(1);

  for (int ci0=0; ci0<8; ++ci0){
    int Tbase = ci0*9;
    // ci0 head: stage WIN(ci0); must fully drain (WIN needed this tap; it's newest in queue)
    const unsigned short* wsrc = ypad + ((size_t)(b*8 + ci0)*256)*64;
    #pragma unroll
    for (int r=0;r<4;++r){
      int L = r*512 + t;
      int row = L>>3, cs = ((L&7)^(row&7))*8;
      gl16(wsrc + row*64 + cs, WIN + L*16);
    }
    asm volatile("s_waitcnt vmcnt(0)" ::: "memory");
    __builtin_amdgcn_s_barrier();
    __builtin_amdgcn_sched_barrier(0);
    for (int tap=0; tap<9; ++tap){
      int T = Tbase + tap;
      char* Acur = AB[T%3];
      bool pre = (T+2 < 72);
      if (pre) STG_A(T+2);
      int kh = tap/3, kw = tap - kh*3;
      bf16x8 ah[4];
      #pragma unroll
      for (int m=0;m<4;++m){
        int row = wm*64 + m*16 + fr;
        ah[m] = *(const bf16x8*)(Acur + row*128 + (((wks*4+fq)^(row&7))<<4));
      }
      int col = frB + kw;
      __builtin_amdgcn_s_setprio(1);
      #pragma unroll
      for (int n=0;n<7;++n){
        int prow = (wn*7 + n + kh)*16 + col;
        bf16x8 bf = *(const bf16x8*)(WIN + prow*128 + (((wks*4+fq)^(prow&7))<<4));
        #pragma unroll
        for (int m=0;m<4;++m)
          acc[m][n] = __builtin_amdgcn_mfma_f32_16x16x32_bf16(ah[m], bf, acc[m][n],0,0,0);
      }
      __builtin_amdgcn_s_setprio(0);
      // counted wait: keep A(T+2) in flight, ensure A(T+1) landed; tail taps drain
      if (pre) { asm volatile("s_waitcnt vmcnt(2)" ::: "memory"); }
      else     { asm volatile("s_waitcnt vmcnt(0)" ::: "memory"); }
      __builtin_amdgcn_s_barrier();
      __builtin_amdgcn_sched_barrier(0);
    }
  }
  // exchange wks=1 partial sums into wks=0 waves (2 halves of m to fit LDS; overlays WIN/AB, dead)
  #pragma unroll
  for (int half=0; half<2; ++half){
    if (wks){
      #pragma unroll
      for (int m2=0;m2<2;++m2)
        #pragma unroll
        for (int n=0;n<7;++n)
          *(f32x4*)(lds + (((size_t)((wm*2+wn)*14 + m2*7 + n))*64 + lane)*16) = acc[half*2+m2][n];
    }
    __syncthreads();
    if (!wks){
      #pragma unroll
      for (int m2=0;m2<2;++m2)
        #pragma unroll
        for (int n=0;n<7;++n){
          f32x4 o = *(const f32x4*)(lds + (((size_t)((wm*2+wn)*14 + m2*7 + n))*64 + lane)*16);
          acc[half*2+m2][n] += o;
        }
    }
    __syncthreads();
  }
  const float* s2 = par+1024; const float* t2 = par+1536;
  float ps[4][4];
  if (!wks){
    #pragma unroll
    for (int m=0;m<4;++m){
      int cb = c0 + wm*64 + m*16 + fq*4;
      #pragma unroll
      for (int j=0;j<4;++j){
        float sc = s2[cb+j], sh = t2[cb+j];
        float s = 0.f;
        #pragma unroll
        for (int n=0;n<7;++n)
          s += fmaxf(acc[m][n][j]*sc + sh, 0.f);
        ps[m][j] = pok ? s : 0.f;
      }
    }
    #pragma unroll
    for (int off=1; off<16; off<<=1)
      #pragma unroll
      for (int m=0;m<4;++m)
        #pragma unroll
        for (int j=0;j<4;++j)
          ps[m][j] += __shfl_xor(ps[m][j], off, 64);
  }
  float* part = (float*)lds;
  if (!wks && fr == 0){
    #pragma unroll
    for (int m=0;m<4;++m)
      #pragma unroll
      for (int j=0;j<4;++j)
        part[wn*128 + wm*64 + m*16 + fq*4 + j] = ps[m][j];
  }
  __syncthreads();
  if (t < 128)
    zbar[(size_t)b*512 + c0 + t] = part[t] + part[128 + t];
}

// ---------------- fc1(relu) + fc2 ----------------
__global__ __launch_bounds__(256) void k_fc(const float* __restrict__ zbar,
        const float* __restrict__ fc1T, const float* __restrict__ fc1b,
        const float* __restrict__ fc2T, const float* __restrict__ fc2b,
        float* __restrict__ out){
  __shared__ float zb[512];
  __shared__ float hl[200];
  int b = blockIdx.x, t = threadIdx.x;
  zb[t]     = zbar[(size_t)b*512 + t]       * (1.f/196.f);
  zb[t+256] = zbar[(size_t)b*512 + t + 256] * (1.f/196.f);
  __syncthreads();
  if (t < 200){
    float acc = fc1b[t];
    for (int k=0;k<512;++k) acc += zb[k]*fc1T[k*200+t];
    hl[t] = fmaxf(acc, 0.f);
  }
  __syncthreads();
  if (t < 200){
    float acc = fc2b[t];
    for (int k=0;k<200;++k) acc += hl[k]*fc2T[k*200+t];
    out[(size_t)b*200 + t] = acc;
  }
}

extern "C" void kernel_launch(void* const* d_in, const int* in_sizes, int n_in,
                              void* d_out, int out_size, void* d_ws, size_t ws_size,
                              hipStream_t stream) {
  const float* feature  = (const float*)d_in[0];
  const float* w_reduce = (const float*)d_in[1];
  const float* b_reduce = (const float*)d_in[2];
  const float* g1  = (const float*)d_in[3];
  const float* be1 = (const float*)d_in[4];
  const float* m1  = (const float*)d_in[5];
  const float* v1  = (const float*)d_in[6];
  const float* w3  = (const float*)d_in[7];
  const float* b3  = (const float*)d_in[8];
  const float* g2  = (const float*)d_in[9];
  const float* be2 = (const float*)d_in[10];
  const float* m2  = (const float*)d_in[11];
  const float* v2  = (const float*)d_in[12];
  const float* fc1w = (const float*)d_in[13];
  const float* fc1b = (const float*)d_in[14];
  const float* fc2w = (const float*)d_in[15];
  const float* fc2b = (const float*)d_in[16];

  char* ws = (char*)d_ws;
  unsigned short* fhi  = (unsigned short*)(ws + O_FHI);
  unsigned short* flo  = (unsigned short*)(ws + O_FLO);
  float*          xxt  = (float*)(ws + O_FHI);      // aliases fhi (dead after conv1)
  unsigned short* xhi  = (unsigned short*)(ws + O_XHI);
  unsigned short* xlo  = (unsigned short*)(ws + O_XLO);
  unsigned short* ypad = (unsigned short*)(ws + O_XLO);  // aliases xlo (dead after xxt)
  unsigned short* xT   = (unsigned short*)(ws + O_XT);
  unsigned short* amat = (unsigned short*)(ws + O_AMAT);
  unsigned short* wh   = (unsigned short*)(ws + O_WH);
  unsigned short* wl   = (unsigned short*)(ws + O_WL);
  unsigned short* w3c  = (unsigned short*)(ws + O_W3B);
  float* par  = (float*)(ws + O_PAR);
  float* fc1T = (float*)(ws + O_FC1T);
  float* fc2T = (float*)(ws + O_FC2T);
  float* zbar = (float*)(ws + O_ZBAR);

  k_prep<<<14127, 256, 0, stream>>>(w_reduce, wh, wl, w3, w3c,
      fc1w, fc1T, fc2w, fc2T,
      b_reduce, g1, be1, m1, v1, b3, g2, be2, m2, v2, par, xhi, xlo);

  k_featT<<<dim3(7,32,128), 256, 0, stream>>>(feature, fhi, flo);
  k_conv1<<<784, 256, 0, stream>>>(fhi, flo, wh, wl, par, xhi, xlo, xT);

  k_xxt<<<1280, 256, 0, stream>>>(xhi, xlo, xxt);
  k_softmax<<<16384, 256, 0, stream>>>(xxt, amat);

  k_pv<<<1024, 256, 0, stream>>>(amat, xT, ypad);   // also zeroes ypad borders
  k_conv3<<<512, 512, 0, stream>>>(ypad, w3c, par, zbar);
  k_fc<<<128, 256, 0, stream>>>(zbar, fc1T, fc1b, fc2T, fc2b, (float*)d_out);
}